// Round 2
// baseline (20090.988 us; speedup 1.0000x reference)
//
#include <hip/hip_runtime.h>
#include <math.h>

// ---------------- problem constants ----------------
#define BB    8
#define CC    2
#define NTOK  1024   // FP*TP
#define PVC   256    // C*PF*PT
#define DDC   768
#define HHC   12
#define LLC   8
#define BN    (BB*NTOK)          // 8192
#define RES_SCALE 0.70710678118654752f
#define LN10K 9.210340371976184f // ln(10000)

typedef __attribute__((ext_vector_type(8))) short bhalf8;
typedef __attribute__((ext_vector_type(4))) float floatx4;

// f32 -> bf16 round-to-nearest-even
__device__ __forceinline__ unsigned short f2bf(float f) {
    union { float f; unsigned int u; } v; v.f = f;
    unsigned int r = (v.u + 0x7FFFu + ((v.u >> 16) & 1u)) >> 16;
    return (unsigned short)r;
}
__device__ __forceinline__ unsigned int pk2(float x, float y) {
    return (unsigned int)f2bf(x) | ((unsigned int)f2bf(y) << 16);
}

// ============================================================
// weight transpose + bf16 convert: W(K,N) f32 -> Wt(N,K) bf16
// block 32x8, grid (N/32, K/32, layers)
// ============================================================
__global__ __launch_bounds__(256) void k_transpose(
    const float* __restrict__ W, unsigned short* __restrict__ Wt, int K, int N)
{
    __shared__ float tile[32][33];
    int n0 = blockIdx.x * 32, k0 = blockIdx.y * 32;
    const float* Wl = W + (size_t)blockIdx.z * K * N;
    unsigned short* Wtl = Wt + (size_t)blockIdx.z * K * N;
    int tx = threadIdx.x & 31, ty = threadIdx.x >> 5;   // 32 x 8
#pragma unroll
    for (int i = 0; i < 32; i += 8)
        tile[ty + i][tx] = Wl[(size_t)(k0 + ty + i) * N + n0 + tx];
    __syncthreads();
#pragma unroll
    for (int i = 0; i < 32; i += 8)
        Wtl[(size_t)(n0 + ty + i) * K + k0 + tx] = f2bf(tile[tx][ty + i]);
}

// ============================================================
// MFMA GEMM: C = epi(A(M x K, f32, stride lda) @ Wt^T)
// Wt is (Nc x K) bf16 row-major (i.e. W transposed).
// 128x128 tile, BK=32, 4 waves each 64x64 (4x4 frags 16x16x32)
// ============================================================
__global__ __launch_bounds__(256) void k_gemm_bf16(
    const float* __restrict__ A, int lda,
    const unsigned short* __restrict__ Wt,
    const float* __restrict__ bias,
    const float* __restrict__ addN,   // (NTOK x Nc), idx row&1023
    const float* __restrict__ addB,   // (BB x Nc), idx row>>10
    const float* __restrict__ resid,  // (M x Nc)
    const float* __restrict__ gate,   // gate + (row>>10)*gstride + c
    int gstride, int act, float res_scale,
    float* __restrict__ Cout, int K, int Nc)
{
    __shared__ uint4 As[512];   // granule [kg 0..3][m 0..127], 16B = k(8) bf16
    __shared__ uint4 Bs[512];   // granule [kg][n]

    const int tid  = threadIdx.x;
    const int lane = tid & 63;
    const int wid  = tid >> 6;
    const int wr   = wid >> 1, wc = wid & 1;
    const int row0 = blockIdx.y * 128, col0 = blockIdx.x * 128;

    const int sm_ = tid >> 2;   // 0..63  (row/col within tile)
    const int skq = tid & 3;    // 0..3   (k-granule)

    floatx4 acc[4][4];
#pragma unroll
    for (int i = 0; i < 4; i++)
#pragma unroll
        for (int j = 0; j < 4; j++) acc[i][j] = (floatx4){0.f, 0.f, 0.f, 0.f};

    const float* Ap  = A  + (size_t)(row0 + sm_) * lda + skq * 8;
    const float* Ap2 = Ap + (size_t)64 * lda;
    const unsigned short* Bp  = Wt + (size_t)(col0 + sm_) * K + skq * 8;
    const unsigned short* Bp2 = Bp + (size_t)64 * K;

    const int rbase = (lane >> 4) * 128 + (lane & 15);

    for (int k0 = 0; k0 < K; k0 += 32) {
        float4 a0 = *(const float4*)(Ap  + k0);
        float4 a1 = *(const float4*)(Ap  + k0 + 4);
        float4 a2 = *(const float4*)(Ap2 + k0);
        float4 a3 = *(const float4*)(Ap2 + k0 + 4);
        uint4  b0 = *(const uint4*)(Bp  + k0);
        uint4  b1 = *(const uint4*)(Bp2 + k0);
        As[skq * 128 + sm_]      = make_uint4(pk2(a0.x,a0.y), pk2(a0.z,a0.w),
                                              pk2(a1.x,a1.y), pk2(a1.z,a1.w));
        As[skq * 128 + 64 + sm_] = make_uint4(pk2(a2.x,a2.y), pk2(a2.z,a2.w),
                                              pk2(a3.x,a3.y), pk2(a3.z,a3.w));
        Bs[skq * 128 + sm_]      = b0;
        Bs[skq * 128 + 64 + sm_] = b1;
        __syncthreads();

        bhalf8 af[4], bfv[4];
#pragma unroll
        for (int rb = 0; rb < 4; rb++)
            af[rb] = __builtin_bit_cast(bhalf8, As[rbase + wr * 64 + rb * 16]);
#pragma unroll
        for (int cb = 0; cb < 4; cb++)
            bfv[cb] = __builtin_bit_cast(bhalf8, Bs[rbase + wc * 64 + cb * 16]);
#pragma unroll
        for (int rb = 0; rb < 4; rb++)
#pragma unroll
            for (int cb = 0; cb < 4; cb++)
                acc[rb][cb] = __builtin_amdgcn_mfma_f32_16x16x32_bf16(
                    af[rb], bfv[cb], acc[rb][cb], 0, 0, 0);
        __syncthreads();
    }

    // epilogue: D layout col = lane&15, row = (lane>>4)*4 + r
    const int lrow = (lane >> 4) * 4;
    const int lcol = lane & 15;
#pragma unroll
    for (int rb = 0; rb < 4; rb++) {
#pragma unroll
        for (int cb = 0; cb < 4; cb++) {
            int col = col0 + wc * 64 + cb * 16 + lcol;
            float bia = bias ? bias[col] : 0.f;
#pragma unroll
            for (int r = 0; r < 4; r++) {
                int row = row0 + wr * 64 + rb * 16 + lrow + r;
                float x = acc[rb][cb][r] + bia;
                if (addN) x += addN[(size_t)(row & (NTOK - 1)) * Nc + col];
                if (addB) x += addB[(size_t)(row >> 10) * Nc + col];
                if (act == 1) x = 0.5f * x * (1.f + erff(x * 0.70710678118654752f));
                if (gate) x = resid[(size_t)row * Nc + col]
                            + res_scale * x * gate[(size_t)(row >> 10) * gstride + col];
                Cout[(size_t)row * Nc + col] = x;
            }
        }
    }
}

// ============================================================
// LayerNorm + adaLN modulation
// ============================================================
__global__ __launch_bounds__(256) void k_ln_mod(
    const float* __restrict__ hbuf, const float* __restrict__ w,
    const float* __restrict__ bln, const float* __restrict__ cond,
    float* __restrict__ out)
{
    __shared__ float sm[4];
    int row  = blockIdx.x;
    int bidx = row >> 10;
    const float* x = hbuf + (size_t)row * DDC;
    int t = threadIdx.x;
    float v0 = x[t], v1 = x[t + 256], v2 = x[t + 512];

    float s = v0 + v1 + v2;
#pragma unroll
    for (int o = 32; o > 0; o >>= 1) s += __shfl_xor(s, o, 64);
    if ((t & 63) == 0) sm[t >> 6] = s;
    __syncthreads();
    float mean = (sm[0] + sm[1] + sm[2] + sm[3]) * (1.f / 768.f);
    __syncthreads();

    float d0 = v0 - mean, d1 = v1 - mean, d2 = v2 - mean;
    float q = d0*d0 + d1*d1 + d2*d2;
#pragma unroll
    for (int o = 32; o > 0; o >>= 1) q += __shfl_xor(q, o, 64);
    if ((t & 63) == 0) sm[t >> 6] = q;
    __syncthreads();
    float var = (sm[0] + sm[1] + sm[2] + sm[3]) * (1.f / 768.f);
    float rs = rsqrtf(var + 1e-5f);

    const float* cb = cond + (size_t)bidx * 2304;
    float* o_ = out + (size_t)row * DDC;
#pragma unroll
    for (int p = 0; p < 3; p++) {
        int c = t + p * 256;
        float d = (p == 0 ? d0 : (p == 1 ? d1 : d2));
        float val = d * rs * w[c] + bln[c];
        o_[c] = val * (1.f + cb[768 + c]) + cb[c];
    }
}

// ============================================================
// Flash attention fp32, 1 thread = 1 q row; no max-subtraction
// (logits provably bounded ~|s|<6 for this model's scales).
// Writes y IN PLACE into the q slot of qkv.
// ============================================================
__global__ __launch_bounds__(256) void k_attn(float* __restrict__ qkv)
{
    __shared__ float Kt[64][68];
    __shared__ float Vt[64][68];
    int blk = blockIdx.x;             // B*H*4
    int qt  = blk & 3;
    int h   = (blk >> 2) % HHC;
    int b   = blk / (4 * HHC);
    int n   = qt * 256 + threadIdx.x;

    float* qp = qkv + ((size_t)(b * NTOK + n)) * 2304 + h * 64;
    float q[64];
#pragma unroll
    for (int d4 = 0; d4 < 16; d4++) {
        float4 t4 = *(const float4*)(qp + d4 * 4);
        q[d4*4+0] = t4.x; q[d4*4+1] = t4.y; q[d4*4+2] = t4.z; q[d4*4+3] = t4.w;
    }
    float l = 0.f;
    float acc[64];
#pragma unroll
    for (int d = 0; d < 64; d++) acc[d] = 0.f;

    int lr = threadIdx.x >> 2;
    int lc = (threadIdx.x & 3) * 16;

    for (int kt = 0; kt < 16; kt++) {
        const float* kp = qkv + ((size_t)(b * NTOK + kt * 64 + lr)) * 2304 + 768 + h * 64 + lc;
        const float* vp = kp + 768;
#pragma unroll
        for (int j = 0; j < 4; j++) {
            *(float4*)&Kt[lr][lc + 4*j] = *(const float4*)(kp + 4*j);
            *(float4*)&Vt[lr][lc + 4*j] = *(const float4*)(vp + 4*j);
        }
        __syncthreads();
        for (int j = 0; j < 64; j++) {
            float s = 0.f;
#pragma unroll
            for (int d = 0; d < 64; d++) s = fmaf(q[d], Kt[j][d], s);
            float p = __expf(s * 0.125f);
            l += p;
#pragma unroll
            for (int d = 0; d < 64; d++) acc[d] = fmaf(p, Vt[j][d], acc[d]);
        }
        __syncthreads();
    }
    float inv = 1.f / l;
#pragma unroll
    for (int d4 = 0; d4 < 16; d4++) {
        *(float4*)(qp + d4 * 4) = make_float4(acc[d4*4+0]*inv, acc[d4*4+1]*inv,
                                              acc[d4*4+2]*inv, acc[d4*4+3]*inv);
    }
}

// ============================================================
// small GEMV for the 8-row conditioning path
// ============================================================
__global__ void k_gemv8(
    const float* __restrict__ in1, const float* __restrict__ in2, int silu_in,
    const float* __restrict__ W, const float* __restrict__ bias,
    float* __restrict__ out, int K, int Nc)
{
    int idx = blockIdx.x * 256 + threadIdx.x;
    if (idx >= 8 * Nc) return;
    int r = idx / Nc, c = idx - r * Nc;
    float s = bias ? bias[c] : 0.f;
    for (int k = 0; k < K; k++) {
        float a = in1[r * K + k];
        if (in2) a += in2[k];
        if (silu_in) a = a / (1.f + __expf(-a));
        s = fmaf(a, W[(size_t)k * Nc + c], s);
    }
    out[r * Nc + c] = s;
}

// ============================================================
__global__ void k_temb(const int* __restrict__ t, float* __restrict__ out)
{
    int idx = blockIdx.x * 256 + threadIdx.x;
    if (idx >= 8 * 768) return;
    int b = idx / 768, j = idx - b * 768;
    float tf = (float)t[b];
    int jj = (j < 384) ? j : (j - 384);
    float freq = __expf((float)jj * (-LN10K / 383.f));
    float a = tf * freq;
    out[idx] = (j < 384) ? sinf(a) : cosf(a);
}

__global__ void k_posemb(float* __restrict__ pos)
{
    int idx = blockIdx.x * 256 + threadIdx.x;
    if (idx >= NTOK * DDC) return;
    int n = idx / DDC, j = idx - n * DDC;
    int fp = n >> 7, tp = n & 127;
    int p  = (j < 384) ? fp : tp;
    int jj = (j < 384) ? j : j - 384;
    int k  = (jj < 192) ? jj : jj - 192;
    float div = __expf((float)k * (-LN10K / 191.f));
    float a = (float)p * div;
    pos[idx] = (jj < 192) ? sinf(a) : cosf(a);
}

__global__ void k_patchify(const float* __restrict__ x, float* __restrict__ tokin)
{
    int idx = blockIdx.x * 256 + threadIdx.x;
    if (idx >= BN * PVC) return;
    int row = idx >> 8, pv = idx & 255;
    int b = row >> 10, n = row & 1023;
    int fp = n >> 7, tp = n & 127;
    int c  = pv >> 7, rem = pv & 127;
    int pf = rem >> 3, pt = rem & 7;
    int f  = fp * 16 + pf;
    int tt = tp * 8 + pt;
    tokin[idx] = x[(((size_t)(b * 2 + c)) * 128 + f) * 1024 + tt];
}

__global__ void k_rope(float* __restrict__ qkv)
{
    int idx = blockIdx.x * 256 + threadIdx.x;  // BN*12*32
    if (idx >= BN * HHC * 32) return;
    int i   = idx & 31;
    int h   = (idx >> 5) % HHC;
    int row = idx / (HHC * 32);
    int n   = row & 1023;
    float* p = qkv + (size_t)row * 2304 + h * 64;
    int j0 = 2 * i, j1 = 2 * i + 1;
    float inv0 = 1.f / powf(10000.f, (float)((j0 & 31) * 2) / 64.f);
    float inv1 = 1.f / powf(10000.f, (float)((j1 & 31) * 2) / 64.f);
    float a0 = (float)n * inv0, a1 = (float)n * inv1;
    float c0 = cosf(a0), s0 = sinf(a0);
    float c1 = cosf(a1), s1 = sinf(a1);
    float q0 = p[j0], q1 = p[j1];
    p[j0] = q0 * c0 - q1 * s0;
    p[j1] = q1 * c1 + q0 * s1;
    float k0 = p[768 + j0], k1 = p[768 + j1];
    p[768 + j0] = k0 * c0 - k1 * s0;
    p[768 + j1] = k1 * c1 + k0 * s1;
}

__global__ void k_unpatch(const float* __restrict__ x, const float* __restrict__ pat,
                          const float* __restrict__ gain, float* __restrict__ out)
{
    int idx = blockIdx.x * 256 + threadIdx.x;
    if (idx >= BB * CC * 128 * 1024) return;
    int t_i = idx & 1023;
    int f   = (idx >> 10) & 127;
    int c   = (idx >> 17) & 1;
    int b   = idx >> 18;
    int fp = f >> 4, pf = f & 15;
    int tp = t_i >> 3, pt = t_i & 7;
    int row = b * 1024 + fp * 128 + tp;
    int pv  = c * 128 + pf * 8 + pt;
    out[idx] = x[idx] + gain[c] * pat[(size_t)row * 256 + pv];
}

// ============================================================
extern "C" void kernel_launch(void* const* d_in, const int* in_sizes, int n_in,
                              void* d_out, int out_size, void* d_ws, size_t ws_size,
                              hipStream_t stream)
{
    const float* x        = (const float*)d_in[0];
    const int*   t        = (const int*)  d_in[1];
    const float* patch_w  = (const float*)d_in[2];
    const float* patch_b  = (const float*)d_in[3];
    const float* tmlp_w1  = (const float*)d_in[4];
    const float* tmlp_b1  = (const float*)d_in[5];
    const float* tmlp_w2  = (const float*)d_in[6];
    const float* tmlp_b2  = (const float*)d_in[7];
    const float* ttok_w   = (const float*)d_in[8];
    const float* ttok_b   = (const float*)d_in[9];
    const float* tokin_w  = (const float*)d_in[10];
    const float* tokin_b  = (const float*)d_in[11];
    const float* bembed   = (const float*)d_in[12];
    const float* ln1_w    = (const float*)d_in[13];
    const float* ln1_b    = (const float*)d_in[14];
    const float* ln2_w    = (const float*)d_in[15];
    const float* ln2_b    = (const float*)d_in[16];
    const float* qkv_w    = (const float*)d_in[17];
    const float* qkv_b    = (const float*)d_in[18];
    const float* aproj_w  = (const float*)d_in[19];
    const float* aproj_b  = (const float*)d_in[20];
    const float* mlp_w1   = (const float*)d_in[21];
    const float* mlp_b1   = (const float*)d_in[22];
    const float* mlp_w2   = (const float*)d_in[23];
    const float* mlp_b2   = (const float*)d_in[24];
    const float* cond1_w  = (const float*)d_in[25];
    const float* cond1_b  = (const float*)d_in[26];
    const float* cond2_w  = (const float*)d_in[27];
    const float* cond2_b  = (const float*)d_in[28];
    const float* unemb_w  = (const float*)d_in[29];
    const float* unemb_b  = (const float*)d_in[30];
    const float* out_gain = (const float*)d_in[31];
    float* out = (float*)d_out;

    // ---- workspace layout ----
    unsigned short* qkv_wt   = (unsigned short*)d_ws;         // 8 x 2304 x 768
    unsigned short* aproj_wt = qkv_wt   + 14155776;           // 8 x 768 x 768
    unsigned short* mlp1_wt  = aproj_wt + 4718592;            // 8 x 3072 x 768
    unsigned short* mlp2_wt  = mlp1_wt  + 18874368;           // 8 x 768 x 3072
    unsigned short* patch_wt = mlp2_wt  + 18874368;           // 768 x 256
    unsigned short* tokin_wt = patch_wt + 196608;             // 768 x 768
    unsigned short* unemb_wt = tokin_wt + 589824;             // 256 x 768
    float* pos   = (float*)(unemb_wt + 196608);               // 1024 x 768
    float* hbuf  = pos  + 786432;                             // 8192 x 768
    float* hn    = hbuf + 6291456;
    float* big   = hn   + 6291456;                            // 8192 x 3072
    float* t_ddpm = big + 25165824;
    float* t_pre  = t_ddpm + 6144;
    float* t_emb  = t_pre  + 6144;
    float* t_tok  = t_emb  + 6144;
    float* tt2    = t_tok  + 6144;
    float* c1     = tt2    + 6144;    // 8 x 2304
    float* c2     = c1     + 18432;

    dim3 blk(256);

    // ---- weight transposes (f32 -> bf16, (K,N) -> (N,K)) ----
    k_transpose<<<dim3(72, 24, 8), blk, 0, stream>>>(qkv_w,  qkv_wt,  768, 2304);
    k_transpose<<<dim3(24, 24, 8), blk, 0, stream>>>(aproj_w, aproj_wt, 768, 768);
    k_transpose<<<dim3(96, 24, 8), blk, 0, stream>>>(mlp_w1, mlp1_wt, 768, 3072);
    k_transpose<<<dim3(24, 96, 8), blk, 0, stream>>>(mlp_w2, mlp2_wt, 3072, 768);
    k_transpose<<<dim3(24,  8, 1), blk, 0, stream>>>(patch_w, patch_wt, 256, 768);
    k_transpose<<<dim3(24, 24, 1), blk, 0, stream>>>(tokin_w, tokin_wt, 768, 768);
    k_transpose<<<dim3( 8, 24, 1), blk, 0, stream>>>(unemb_w, unemb_wt, 768, 256);

    // ---- prologue ----
    k_patchify<<<dim3((BN * PVC + 255) / 256), blk, 0, stream>>>(x, big);
    k_posemb  <<<dim3((NTOK * DDC + 255) / 256), blk, 0, stream>>>(pos);
    k_temb    <<<dim3(24), blk, 0, stream>>>(t, t_ddpm);
    k_gemv8<<<dim3(24), blk, 0, stream>>>(t_ddpm, nullptr, 0, tmlp_w1, tmlp_b1, t_pre, 768, 768);
    k_gemv8<<<dim3(24), blk, 0, stream>>>(t_pre,  nullptr, 1, tmlp_w2, tmlp_b2, t_emb, 768, 768);
    k_gemv8<<<dim3(24), blk, 0, stream>>>(t_emb,  nullptr, 1, ttok_w,  ttok_b,  t_tok, 768, 768);
    k_gemv8<<<dim3(24), blk, 0, stream>>>(t_tok,  nullptr, 0, tokin_w + (size_t)768 * 768, tokin_b, tt2, 768, 768);

    // tok = patchify @ patch_w + patch_b + pos  -> hn
    k_gemm_bf16<<<dim3(6, 64), blk, 0, stream>>>(
        big, 256, patch_wt, patch_b, pos, nullptr, nullptr, nullptr, 0, 0, 1.f,
        hn, 256, 768);
    // h = tok @ tokin_w[:768] + tt2[b]  -> hbuf
    k_gemm_bf16<<<dim3(6, 64), blk, 0, stream>>>(
        hn, 768, tokin_wt, nullptr, nullptr, tt2, nullptr, nullptr, 0, 0, 1.f,
        hbuf, 768, 768);

    // ---- transformer blocks ----
    for (int i = 0; i < LLC; i++) {
        const float* be = bembed + (size_t)i * 768;
        k_gemv8<<<dim3(72), blk, 0, stream>>>(t_emb, be, 1,
            cond1_w + (size_t)i * 768 * 2304, cond1_b + (size_t)i * 2304, c1, 768, 2304);
        k_gemv8<<<dim3(72), blk, 0, stream>>>(t_emb, be, 1,
            cond2_w + (size_t)i * 768 * 2304, cond2_b + (size_t)i * 2304, c2, 768, 2304);

        k_ln_mod<<<dim3(BN), blk, 0, stream>>>(
            hbuf, ln1_w + (size_t)i * 768, ln1_b + (size_t)i * 768, c1, hn);

        k_gemm_bf16<<<dim3(18, 64), blk, 0, stream>>>(
            hn, 768, qkv_wt + (size_t)i * 2304 * 768, qkv_b + (size_t)i * 2304,
            nullptr, nullptr, nullptr, nullptr, 0, 0, 1.f,
            big, 768, 2304);

        k_rope<<<dim3((BN * HHC * 32 + 255) / 256), blk, 0, stream>>>(big);
        k_attn<<<dim3(BB * HHC * 4), blk, 0, stream>>>(big);   // y -> q slot

        // h += RES_SCALE * (y@W + b) * g1
        k_gemm_bf16<<<dim3(6, 64), blk, 0, stream>>>(
            big, 2304, aproj_wt + (size_t)i * 768 * 768, aproj_b + (size_t)i * 768,
            nullptr, nullptr, hbuf, c1 + 1536, 2304, 0, RES_SCALE,
            hbuf, 768, 768);

        k_ln_mod<<<dim3(BN), blk, 0, stream>>>(
            hbuf, ln2_w + (size_t)i * 768, ln2_b + (size_t)i * 768, c2, hn);

        // m1 = gelu(hn @ w1 + b1)
        k_gemm_bf16<<<dim3(24, 64), blk, 0, stream>>>(
            hn, 768, mlp1_wt + (size_t)i * 3072 * 768, mlp_b1 + (size_t)i * 3072,
            nullptr, nullptr, nullptr, nullptr, 0, 1, 1.f,
            big, 768, 3072);

        // h += RES_SCALE * (m1 @ w2 + b2) * g2
        k_gemm_bf16<<<dim3(6, 64), blk, 0, stream>>>(
            big, 3072, mlp2_wt + (size_t)i * 768 * 3072, mlp_b2 + (size_t)i * 768,
            nullptr, nullptr, hbuf, c2 + 1536, 2304, 0, RES_SCALE,
            hbuf, 3072, 768);
    }

    // ---- epilogue ----
    k_gemm_bf16<<<dim3(2, 64), blk, 0, stream>>>(
        hbuf, 768, unemb_wt, unemb_b, nullptr, nullptr, nullptr, nullptr, 0, 0, 1.f,
        big, 768, 256);

    k_unpatch<<<dim3((BB * CC * 128 * 1024 + 255) / 256), blk, 0, stream>>>(
        x, big, out_gain, out);
}

// Round 7
// 5408.054 us; speedup vs baseline: 3.7150x; 3.7150x over previous
//
#include <hip/hip_runtime.h>
#include <math.h>

// ---------------- problem constants ----------------
#define BB    8
#define CC    2
#define NTOK  1024   // FP*TP
#define PVC   256    // C*PF*PT
#define DDC   768
#define HHC   12
#define LLC   8
#define BN    (BB*NTOK)          // 8192
#define RES_SCALE 0.70710678118654752f
#define LN10K 9.210340371976184f // ln(10000)

typedef __attribute__((ext_vector_type(8)))  short bhalf8;
typedef __attribute__((ext_vector_type(4)))  float floatx4;
typedef __attribute__((ext_vector_type(16))) float floatx16;

// f32 -> bf16 round-to-nearest-even
__device__ __forceinline__ unsigned short f2bf(float f) {
    union { float f; unsigned int u; } v; v.f = f;
    unsigned int r = (v.u + 0x7FFFu + ((v.u >> 16) & 1u)) >> 16;
    return (unsigned short)r;
}
__device__ __forceinline__ unsigned int pk2(float x, float y) {
    return (unsigned int)f2bf(x) | ((unsigned int)f2bf(y) << 16);
}

// ============================================================
// weight transpose + bf16 convert: W(K,N) f32 -> Wt(N,K) bf16
// ============================================================
__global__ __launch_bounds__(256) void k_transpose(
    const float* __restrict__ W, unsigned short* __restrict__ Wt, int K, int N)
{
    __shared__ float tile[32][33];
    int n0 = blockIdx.x * 32, k0 = blockIdx.y * 32;
    const float* Wl = W + (size_t)blockIdx.z * K * N;
    unsigned short* Wtl = Wt + (size_t)blockIdx.z * K * N;
    int tx = threadIdx.x & 31, ty = threadIdx.x >> 5;   // 32 x 8
#pragma unroll
    for (int i = 0; i < 32; i += 8)
        tile[ty + i][tx] = Wl[(size_t)(k0 + ty + i) * N + n0 + tx];
    __syncthreads();
#pragma unroll
    for (int i = 0; i < 32; i += 8)
        Wtl[(size_t)(n0 + ty + i) * K + k0 + tx] = f2bf(tile[tx][ty + i]);
}

// ============================================================
// MFMA GEMM: C = epi(A(M x K, f32, stride lda) @ Wt^T)
// Wt is (Nc x K) bf16 row-major. 128x128 tile, BK=32,
// 4 waves each 64x64 (4x4 frags of 16x16x32)
// ============================================================
__global__ __launch_bounds__(256) void k_gemm_bf16(
    const float* __restrict__ A, int lda,
    const unsigned short* __restrict__ Wt,
    const float* __restrict__ bias,
    const float* __restrict__ addN,   // (NTOK x Nc), idx row&1023
    const float* __restrict__ addB,   // (BB x Nc), idx row>>10
    const float* __restrict__ resid,  // (M x Nc)
    const float* __restrict__ gate,   // gate + (row>>10)*gstride + c
    int gstride, int act, float res_scale,
    float* __restrict__ Cout, int K, int Nc)
{
    __shared__ uint4 As[512];   // [kg 0..3][m 0..127], 16B = 8 bf16
    __shared__ uint4 Bs[512];

    const int tid  = threadIdx.x;
    const int lane = tid & 63;
    const int wid  = tid >> 6;
    const int wr   = wid >> 1, wc = wid & 1;
    const int row0 = blockIdx.y * 128, col0 = blockIdx.x * 128;

    const int sm_ = tid >> 2;   // 0..63
    const int skq = tid & 3;    // 0..3

    floatx4 acc[4][4];
#pragma unroll
    for (int i = 0; i < 4; i++)
#pragma unroll
        for (int j = 0; j < 4; j++) acc[i][j] = (floatx4){0.f, 0.f, 0.f, 0.f};

    const float* Ap  = A  + (size_t)(row0 + sm_) * lda + skq * 8;
    const float* Ap2 = Ap + (size_t)64 * lda;
    const unsigned short* Bp  = Wt + (size_t)(col0 + sm_) * K + skq * 8;
    const unsigned short* Bp2 = Bp + (size_t)64 * K;

    const int rbase = (lane >> 4) * 128 + (lane & 15);

    for (int k0 = 0; k0 < K; k0 += 32) {
        float4 a0 = *(const float4*)(Ap  + k0);
        float4 a1 = *(const float4*)(Ap  + k0 + 4);
        float4 a2 = *(const float4*)(Ap2 + k0);
        float4 a3 = *(const float4*)(Ap2 + k0 + 4);
        uint4  b0 = *(const uint4*)(Bp  + k0);
        uint4  b1 = *(const uint4*)(Bp2 + k0);
        As[skq * 128 + sm_]      = make_uint4(pk2(a0.x,a0.y), pk2(a0.z,a0.w),
                                              pk2(a1.x,a1.y), pk2(a1.z,a1.w));
        As[skq * 128 + 64 + sm_] = make_uint4(pk2(a2.x,a2.y), pk2(a2.z,a2.w),
                                              pk2(a3.x,a3.y), pk2(a3.z,a3.w));
        Bs[skq * 128 + sm_]      = b0;
        Bs[skq * 128 + 64 + sm_] = b1;
        __syncthreads();

        bhalf8 af[4], bfv[4];
#pragma unroll
        for (int rb = 0; rb < 4; rb++)
            af[rb] = __builtin_bit_cast(bhalf8, As[rbase + wr * 64 + rb * 16]);
#pragma unroll
        for (int cb = 0; cb < 4; cb++)
            bfv[cb] = __builtin_bit_cast(bhalf8, Bs[rbase + wc * 64 + cb * 16]);
#pragma unroll
        for (int rb = 0; rb < 4; rb++)
#pragma unroll
            for (int cb = 0; cb < 4; cb++)
                acc[rb][cb] = __builtin_amdgcn_mfma_f32_16x16x32_bf16(
                    af[rb], bfv[cb], acc[rb][cb], 0, 0, 0);
        __syncthreads();
    }

    const int lrow = (lane >> 4) * 4;
    const int lcol = lane & 15;
#pragma unroll
    for (int rb = 0; rb < 4; rb++) {
#pragma unroll
        for (int cb = 0; cb < 4; cb++) {
            int col = col0 + wc * 64 + cb * 16 + lcol;
            float bia = bias ? bias[col] : 0.f;
#pragma unroll
            for (int r = 0; r < 4; r++) {
                int row = row0 + wr * 64 + rb * 16 + lrow + r;
                float x = acc[rb][cb][r] + bia;
                if (addN) x += addN[(size_t)(row & (NTOK - 1)) * Nc + col];
                if (addB) x += addB[(size_t)(row >> 10) * Nc + col];
                if (act == 1) x = 0.5f * x * (1.f + erff(x * 0.70710678118654752f));
                if (gate) x = resid[(size_t)row * Nc + col]
                            + res_scale * x * gate[(size_t)(row >> 10) * gstride + col];
                Cout[(size_t)row * Nc + col] = x;
            }
        }
    }
}

// ============================================================
// LayerNorm + adaLN modulation
// ============================================================
__global__ __launch_bounds__(256) void k_ln_mod(
    const float* __restrict__ hbuf, const float* __restrict__ w,
    const float* __restrict__ bln, const float* __restrict__ cond,
    float* __restrict__ out)
{
    __shared__ float sm[4];
    int row  = blockIdx.x;
    int bidx = row >> 10;
    const float* x = hbuf + (size_t)row * DDC;
    int t = threadIdx.x;
    float v0 = x[t], v1 = x[t + 256], v2 = x[t + 512];

    float s = v0 + v1 + v2;
#pragma unroll
    for (int o = 32; o > 0; o >>= 1) s += __shfl_xor(s, o, 64);
    if ((t & 63) == 0) sm[t >> 6] = s;
    __syncthreads();
    float mean = (sm[0] + sm[1] + sm[2] + sm[3]) * (1.f / 768.f);
    __syncthreads();

    float d0 = v0 - mean, d1 = v1 - mean, d2 = v2 - mean;
    float q = d0*d0 + d1*d1 + d2*d2;
#pragma unroll
    for (int o = 32; o > 0; o >>= 1) q += __shfl_xor(q, o, 64);
    if ((t & 63) == 0) sm[t >> 6] = q;
    __syncthreads();
    float var = (sm[0] + sm[1] + sm[2] + sm[3]) * (1.f / 768.f);
    float rs = rsqrtf(var + 1e-5f);

    const float* cb = cond + (size_t)bidx * 2304;
    float* o_ = out + (size_t)row * DDC;
#pragma unroll
    for (int p = 0; p < 3; p++) {
        int c = t + p * 256;
        float d = (p == 0 ? d0 : (p == 1 ? d1 : d2));
        float val = d * rs * w[c] + bln[c];
        o_[c] = val * (1.f + cb[768 + c]) + cb[c];
    }
}

// ============================================================
// MFMA flash attention (bf16 inputs, f32 accum, no max-sub).
// Block = one (b,h), 128 q rows (4 waves x 32 q). KV tiles of 32.
// Swapped QK^T: S^T = mfma(K, Q^T) so P is lane-local per q.
// PV key-permutation absorbed into V's LDS granule layout.
// Writes y in place into the q slot of qkv.
// ============================================================
__global__ __launch_bounds__(256) void k_attn_mfma(float* __restrict__ qkv)
{
    __shared__ uint4 Ks[256];        // [g=kf*2+hi][key 0..31]  4KB
    __shared__ uint4 Vt[256];        // [gv=ks*2+hi][d 0..63]   4KB
    __shared__ float linv_sm[4][32];

    const int tid = threadIdx.x;
    const int lane = tid & 63;
    const int wid = tid >> 6;
    const int hi  = lane >> 5;
    const int l31 = lane & 31;

    const int blk = blockIdx.x;          // 768 = 8b * 12h * 8qt
    const int qt  = blk & 7;
    const int h   = (blk >> 3) % HHC;
    const int b   = blk / (8 * HHC);
    const int rowQ  = b * NTOK + qt * 128 + wid * 32;   // wave's q base row
    const int rowKV = b * NTOK;

    // ---- Q into B-fragments (held in regs for whole kernel) ----
    // B layout: col=q=l31, k = kf*16 + hi*8 + j
    uint4 qf[4];
    {
        const float* qp = qkv + (size_t)(rowQ + l31) * 2304 + h * 64;
#pragma unroll
        for (int kf = 0; kf < 4; kf++) {
            float4 f0 = *(const float4*)(qp + kf * 16 + hi * 8);
            float4 f1 = *(const float4*)(qp + kf * 16 + hi * 8 + 4);
            qf[kf] = make_uint4(pk2(f0.x,f0.y), pk2(f0.z,f0.w),
                                pk2(f1.x,f1.y), pk2(f1.z,f1.w));
        }
    }

    floatx16 yacc0, yacc1;
#pragma unroll
    for (int r = 0; r < 16; r++) { yacc0[r] = 0.f; yacc1[r] = 0.f; }
    float lpart = 0.f;

    const int skey = tid >> 3, sj = tid & 7;       // K staging: 32 keys x 8 chunks
    const int sd = tid & 63, sgv = tid >> 6;       // V staging: 64 d x 4 granules
    const int kb = (sgv >> 1) * 16 + (sgv & 1) * 4;

    for (int kv = 0; kv < 32; kv++) {
        __syncthreads();
        // stage K tile: Ks[sj][skey] = K[key=skey][feats sj*8..sj*8+7]
        {
            const float* kp = qkv + (size_t)(rowKV + kv * 32 + skey) * 2304
                              + 768 + h * 64 + sj * 8;
            float4 f0 = *(const float4*)kp;
            float4 f1 = *(const float4*)(kp + 4);
            Ks[sj * 32 + skey] = make_uint4(pk2(f0.x,f0.y), pk2(f0.z,f0.w),
                                            pk2(f1.x,f1.y), pk2(f1.z,f1.w));
        }
        // stage V transposed+permuted: Vt[sgv][sd] slots j hold
        // keys kb + (j&3) + 8*(j>>2)
        {
            const float* vb = qkv + (size_t)(rowKV + kv * 32) * 2304
                              + 1536 + h * 64 + sd;
            float e0 = vb[(size_t)(kb + 0) * 2304];
            float e1 = vb[(size_t)(kb + 1) * 2304];
            float e2 = vb[(size_t)(kb + 2) * 2304];
            float e3 = vb[(size_t)(kb + 3) * 2304];
            float e4 = vb[(size_t)(kb + 8) * 2304];
            float e5 = vb[(size_t)(kb + 9) * 2304];
            float e6 = vb[(size_t)(kb + 10) * 2304];
            float e7 = vb[(size_t)(kb + 11) * 2304];
            Vt[sgv * 64 + sd] = make_uint4(pk2(e0,e1), pk2(e2,e3),
                                           pk2(e4,e5), pk2(e6,e7));
        }
        __syncthreads();

        // ---- QK^T: S^T[key][q], key = (r&3)+8*(r>>2)+4*hi ----
        floatx16 sacc;
#pragma unroll
        for (int r = 0; r < 16; r++) sacc[r] = 0.f;
#pragma unroll
        for (int kf = 0; kf < 4; kf++) {
            uint4 kfrag = Ks[(kf * 2 + hi) * 32 + l31];
            sacc = __builtin_amdgcn_mfma_f32_32x32x16_bf16(
                __builtin_bit_cast(bhalf8, kfrag),
                __builtin_bit_cast(bhalf8, qf[kf]), sacc, 0, 0, 0);
        }

        // ---- softmax numerator (bounded logits: no max-sub) ----
        float pr[16];
        float psum = 0.f;
#pragma unroll
        for (int r = 0; r < 16; r++) {
            pr[r] = __expf(sacc[r] * 0.125f);
            psum += pr[r];
        }
        lpart += psum;

        // pack P to bf16 pairs (pure C++ RNE pack; no inline asm)
        uint4 pa0 = make_uint4(pk2(pr[0], pr[1]),  pk2(pr[2], pr[3]),
                               pk2(pr[4], pr[5]),  pk2(pr[6], pr[7]));
        uint4 pa1 = make_uint4(pk2(pr[8], pr[9]),  pk2(pr[10], pr[11]),
                               pk2(pr[12], pr[13]), pk2(pr[14], pr[15]));

        // ---- PV: Y[q][d] += P * V  (permuted key order matches Vt) ----
        {
            uint4 v00 = Vt[(0 * 2 + hi) * 64 +  0 + l31];
            uint4 v10 = Vt[(1 * 2 + hi) * 64 +  0 + l31];
            uint4 v01 = Vt[(0 * 2 + hi) * 64 + 32 + l31];
            uint4 v11 = Vt[(1 * 2 + hi) * 64 + 32 + l31];
            yacc0 = __builtin_amdgcn_mfma_f32_32x32x16_bf16(
                __builtin_bit_cast(bhalf8, pa0), __builtin_bit_cast(bhalf8, v00), yacc0, 0,0,0);
            yacc0 = __builtin_amdgcn_mfma_f32_32x32x16_bf16(
                __builtin_bit_cast(bhalf8, pa1), __builtin_bit_cast(bhalf8, v10), yacc0, 0,0,0);
            yacc1 = __builtin_amdgcn_mfma_f32_32x32x16_bf16(
                __builtin_bit_cast(bhalf8, pa0), __builtin_bit_cast(bhalf8, v01), yacc1, 0,0,0);
            yacc1 = __builtin_amdgcn_mfma_f32_32x32x16_bf16(
                __builtin_bit_cast(bhalf8, pa1), __builtin_bit_cast(bhalf8, v11), yacc1, 0,0,0);
        }
    }

    // ---- denominator: partner lane (l^32) holds the other 16 keys ----
    float ltot = lpart + __shfl_xor(lpart, 32, 64);
    if (hi == 0) linv_sm[wid][l31] = 1.f / ltot;
    __syncthreads();

    float* orow = qkv + (size_t)rowQ * 2304 + h * 64;
#pragma unroll
    for (int r = 0; r < 16; r++) {
        int q_ = (r & 3) + 8 * (r >> 2) + 4 * hi;
        float inv = linv_sm[wid][q_];
        orow[(size_t)q_ * 2304 + l31]      = yacc0[r] * inv;
        orow[(size_t)q_ * 2304 + 32 + l31] = yacc1[r] * inv;
    }
}

// ============================================================
// small GEMV for the 8-row conditioning path (split accumulators)
// ============================================================
__global__ void k_gemv8(
    const float* __restrict__ in1, const float* __restrict__ in2, int silu_in,
    const float* __restrict__ W, const float* __restrict__ bias,
    float* __restrict__ out, int K, int Nc)
{
    int idx = blockIdx.x * 256 + threadIdx.x;
    if (idx >= 8 * Nc) return;
    int r = idx / Nc, c = idx - r * Nc;
    float s0 = 0.f, s1 = 0.f, s2 = 0.f, s3 = 0.f;
    for (int k = 0; k < K; k += 4) {
#pragma unroll
        for (int u = 0; u < 4; u++) {
            float a = in1[r * K + k + u];
            if (in2) a += in2[k + u];
            if (silu_in) a = a / (1.f + __expf(-a));
            float wv = W[(size_t)(k + u) * Nc + c];
            if (u == 0) s0 = fmaf(a, wv, s0);
            else if (u == 1) s1 = fmaf(a, wv, s1);
            else if (u == 2) s2 = fmaf(a, wv, s2);
            else s3 = fmaf(a, wv, s3);
        }
    }
    float s = (bias ? bias[c] : 0.f) + ((s0 + s1) + (s2 + s3));
    out[r * Nc + c] = s;
}

// ============================================================
// silu_te[i][b][:] = silu(t_emb[b] + bembed[i])
// ============================================================
__global__ void k_silu_te(const float* __restrict__ t_emb,
                          const float* __restrict__ bembed,
                          float* __restrict__ ste)
{
    int idx = blockIdx.x * 256 + threadIdx.x;   // 8*8*768
    if (idx >= LLC * 8 * 768) return;
    int c = idx % 768;
    int bb = (idx / 768) & 7;
    int i  = idx / 6144;
    float x = t_emb[bb * 768 + c] + bembed[i * 768 + c];
    ste[idx] = x / (1.f + __expf(-x));
}

// ============================================================
// batched conditioning: for each (layer, cond): out(8x2304) =
// ste[layer] @ condW[layer] + condB[layer]
// grid (9 colblocks, 2 conds, 8 layers), block 256
// ============================================================
__global__ __launch_bounds__(256) void k_cond(
    const float* __restrict__ ste,
    const float* __restrict__ c1w, const float* __restrict__ c1b,
    const float* __restrict__ c2w, const float* __restrict__ c2b,
    float* __restrict__ c1o, float* __restrict__ c2o)
{
    __shared__ float As[768][8];     // [k][r] 24KB
    const int cb = blockIdx.x, cond = blockIdx.y, lay = blockIdx.z;
    const float* W  = (cond ? c2w : c1w) + (size_t)lay * 768 * 2304;
    const float* Bv = (cond ? c2b : c1b) + (size_t)lay * 2304;
    float* Ov = (cond ? c2o : c1o) + (size_t)lay * 8 * 2304;

    for (int i = threadIdx.x; i < 6144; i += 256) {
        int k = i >> 3, r = i & 7;
        As[k][r] = ste[(size_t)lay * 6144 + r * 768 + k];
    }
    __syncthreads();

    int c = cb * 256 + threadIdx.x;
    float acc[8];
#pragma unroll
    for (int r = 0; r < 8; r++) acc[r] = 0.f;
#pragma unroll 4
    for (int k = 0; k < 768; k++) {
        float wvv = W[(size_t)k * 2304 + c];
        float4 A0 = *(const float4*)&As[k][0];
        float4 A1 = *(const float4*)&As[k][4];
        acc[0] = fmaf(A0.x, wvv, acc[0]);
        acc[1] = fmaf(A0.y, wvv, acc[1]);
        acc[2] = fmaf(A0.z, wvv, acc[2]);
        acc[3] = fmaf(A0.w, wvv, acc[3]);
        acc[4] = fmaf(A1.x, wvv, acc[4]);
        acc[5] = fmaf(A1.y, wvv, acc[5]);
        acc[6] = fmaf(A1.z, wvv, acc[6]);
        acc[7] = fmaf(A1.w, wvv, acc[7]);
    }
    float bv = Bv[c];
#pragma unroll
    for (int r = 0; r < 8; r++) Ov[r * 2304 + c] = acc[r] + bv;
}

// ============================================================
__global__ void k_temb(const int* __restrict__ t, float* __restrict__ out)
{
    int idx = blockIdx.x * 256 + threadIdx.x;
    if (idx >= 8 * 768) return;
    int b = idx / 768, j = idx - b * 768;
    float tf = (float)t[b];
    int jj = (j < 384) ? j : (j - 384);
    float freq = __expf((float)jj * (-LN10K / 383.f));
    float a = tf * freq;
    out[idx] = (j < 384) ? sinf(a) : cosf(a);
}

__global__ void k_posemb(float* __restrict__ pos)
{
    int idx = blockIdx.x * 256 + threadIdx.x;
    if (idx >= NTOK * DDC) return;
    int n = idx / DDC, j = idx - n * DDC;
    int fp = n >> 7, tp = n & 127;
    int p  = (j < 384) ? fp : tp;
    int jj = (j < 384) ? j : j - 384;
    int k  = (jj < 192) ? jj : jj - 192;
    float div = __expf((float)k * (-LN10K / 191.f));
    float a = (float)p * div;
    pos[idx] = (jj < 192) ? sinf(a) : cosf(a);
}

__global__ void k_patchify(const float* __restrict__ x, float* __restrict__ tokin)
{
    int idx = blockIdx.x * 256 + threadIdx.x;
    if (idx >= BN * PVC) return;
    int row = idx >> 8, pv = idx & 255;
    int b = row >> 10, n = row & 1023;
    int fp = n >> 7, tp = n & 127;
    int c  = pv >> 7, rem = pv & 127;
    int pf = rem >> 3, pt = rem & 7;
    int f  = fp * 16 + pf;
    int tt = tp * 8 + pt;
    tokin[idx] = x[(((size_t)(b * 2 + c)) * 128 + f) * 1024 + tt];
}

__global__ void k_rope(float* __restrict__ qkv)
{
    int idx = blockIdx.x * 256 + threadIdx.x;  // BN*12*32
    if (idx >= BN * HHC * 32) return;
    int i   = idx & 31;
    int h   = (idx >> 5) % HHC;
    int row = idx / (HHC * 32);
    int n   = row & 1023;
    float* p = qkv + (size_t)row * 2304 + h * 64;
    int j0 = 2 * i, j1 = 2 * i + 1;
    float inv0 = 1.f / powf(10000.f, (float)((j0 & 31) * 2) / 64.f);
    float inv1 = 1.f / powf(10000.f, (float)((j1 & 31) * 2) / 64.f);
    float a0 = (float)n * inv0, a1 = (float)n * inv1;
    float c0 = cosf(a0), s0 = sinf(a0);
    float c1 = cosf(a1), s1 = sinf(a1);
    float q0 = p[j0], q1 = p[j1];
    p[j0] = q0 * c0 - q1 * s0;
    p[j1] = q1 * c1 + q0 * s1;
    float k0 = p[768 + j0], k1 = p[768 + j1];
    p[768 + j0] = k0 * c0 - k1 * s0;
    p[768 + j1] = k1 * c1 + k0 * s1;
}

__global__ void k_unpatch(const float* __restrict__ x, const float* __restrict__ pat,
                          const float* __restrict__ gain, float* __restrict__ out)
{
    int idx = blockIdx.x * 256 + threadIdx.x;
    if (idx >= BB * CC * 128 * 1024) return;
    int t_i = idx & 1023;
    int f   = (idx >> 10) & 127;
    int c   = (idx >> 17) & 1;
    int b   = idx >> 18;
    int fp = f >> 4, pf = f & 15;
    int tp = t_i >> 3, pt = t_i & 7;
    int row = b * 1024 + fp * 128 + tp;
    int pv  = c * 128 + pf * 8 + pt;
    out[idx] = x[idx] + gain[c] * pat[(size_t)row * 256 + pv];
}

// ============================================================
extern "C" void kernel_launch(void* const* d_in, const int* in_sizes, int n_in,
                              void* d_out, int out_size, void* d_ws, size_t ws_size,
                              hipStream_t stream)
{
    const float* x        = (const float*)d_in[0];
    const int*   t        = (const int*)  d_in[1];
    const float* patch_w  = (const float*)d_in[2];
    const float* patch_b  = (const float*)d_in[3];
    const float* tmlp_w1  = (const float*)d_in[4];
    const float* tmlp_b1  = (const float*)d_in[5];
    const float* tmlp_w2  = (const float*)d_in[6];
    const float* tmlp_b2  = (const float*)d_in[7];
    const float* ttok_w   = (const float*)d_in[8];
    const float* ttok_b   = (const float*)d_in[9];
    const float* tokin_w  = (const float*)d_in[10];
    const float* tokin_b  = (const float*)d_in[11];
    const float* bembed   = (const float*)d_in[12];
    const float* ln1_w    = (const float*)d_in[13];
    const float* ln1_b    = (const float*)d_in[14];
    const float* ln2_w    = (const float*)d_in[15];
    const float* ln2_b    = (const float*)d_in[16];
    const float* qkv_w    = (const float*)d_in[17];
    const float* qkv_b    = (const float*)d_in[18];
    const float* aproj_w  = (const float*)d_in[19];
    const float* aproj_b  = (const float*)d_in[20];
    const float* mlp_w1   = (const float*)d_in[21];
    const float* mlp_b1   = (const float*)d_in[22];
    const float* mlp_w2   = (const float*)d_in[23];
    const float* mlp_b2   = (const float*)d_in[24];
    const float* cond1_w  = (const float*)d_in[25];
    const float* cond1_b  = (const float*)d_in[26];
    const float* cond2_w  = (const float*)d_in[27];
    const float* cond2_b  = (const float*)d_in[28];
    const float* unemb_w  = (const float*)d_in[29];
    const float* unemb_b  = (const float*)d_in[30];
    const float* out_gain = (const float*)d_in[31];
    float* out = (float*)d_out;

    // ---- workspace layout ----
    unsigned short* qkv_wt   = (unsigned short*)d_ws;         // 8 x 2304 x 768
    unsigned short* aproj_wt = qkv_wt   + 14155776;           // 8 x 768 x 768
    unsigned short* mlp1_wt  = aproj_wt + 4718592;            // 8 x 3072 x 768
    unsigned short* mlp2_wt  = mlp1_wt  + 18874368;           // 8 x 768 x 3072
    unsigned short* patch_wt = mlp2_wt  + 18874368;           // 768 x 256
    unsigned short* tokin_wt = patch_wt + 196608;             // 768 x 768
    unsigned short* unemb_wt = tokin_wt + 589824;             // 256 x 768
    float* pos   = (float*)(unemb_wt + 196608);               // 1024 x 768
    float* hbuf  = pos  + 786432;                             // 8192 x 768
    float* hn    = hbuf + 6291456;
    float* big   = hn   + 6291456;                            // 8192 x 3072
    float* t_ddpm = big + 25165824;
    float* t_pre  = t_ddpm + 6144;
    float* t_emb  = t_pre  + 6144;
    float* t_tok  = t_emb  + 6144;
    float* tt2    = t_tok  + 6144;
    float* ste    = tt2    + 6144;     // 8 x 8 x 768
    float* c1     = ste    + 49152;    // 8 x 8 x 2304
    float* c2     = c1     + 147456;

    dim3 blk(256);

    // ---- weight transposes (f32 -> bf16, (K,N) -> (N,K)) ----
    k_transpose<<<dim3(72, 24, 8), blk, 0, stream>>>(qkv_w,  qkv_wt,  768, 2304);
    k_transpose<<<dim3(24, 24, 8), blk, 0, stream>>>(aproj_w, aproj_wt, 768, 768);
    k_transpose<<<dim3(96, 24, 8), blk, 0, stream>>>(mlp_w1, mlp1_wt, 768, 3072);
    k_transpose<<<dim3(24, 96, 8), blk, 0, stream>>>(mlp_w2, mlp2_wt, 3072, 768);
    k_transpose<<<dim3(24,  8, 1), blk, 0, stream>>>(patch_w, patch_wt, 256, 768);
    k_transpose<<<dim3(24, 24, 1), blk, 0, stream>>>(tokin_w, tokin_wt, 768, 768);
    k_transpose<<<dim3( 8, 24, 1), blk, 0, stream>>>(unemb_w, unemb_wt, 768, 256);

    // ---- prologue ----
    k_patchify<<<dim3((BN * PVC + 255) / 256), blk, 0, stream>>>(x, big);
    k_posemb  <<<dim3((NTOK * DDC + 255) / 256), blk, 0, stream>>>(pos);
    k_temb    <<<dim3(24), blk, 0, stream>>>(t, t_ddpm);
    k_gemv8<<<dim3(24), blk, 0, stream>>>(t_ddpm, nullptr, 0, tmlp_w1, tmlp_b1, t_pre, 768, 768);
    k_gemv8<<<dim3(24), blk, 0, stream>>>(t_pre,  nullptr, 1, tmlp_w2, tmlp_b2, t_emb, 768, 768);
    k_gemv8<<<dim3(24), blk, 0, stream>>>(t_emb,  nullptr, 1, ttok_w,  ttok_b,  t_tok, 768, 768);
    k_gemv8<<<dim3(24), blk, 0, stream>>>(t_tok,  nullptr, 0, tokin_w + (size_t)768 * 768, tokin_b, tt2, 768, 768);

    // conditioning for all layers, up front
    k_silu_te<<<dim3(192), blk, 0, stream>>>(t_emb, bembed, ste);
    k_cond<<<dim3(9, 2, 8), blk, 0, stream>>>(ste, cond1_w, cond1_b, cond2_w, cond2_b, c1, c2);

    // tok = patchify @ patch_w + patch_b + pos  -> hn
    k_gemm_bf16<<<dim3(6, 64), blk, 0, stream>>>(
        big, 256, patch_wt, patch_b, pos, nullptr, nullptr, nullptr, 0, 0, 1.f,
        hn, 256, 768);
    // h = tok @ tokin_w[:768] + tt2[b]  -> hbuf
    k_gemm_bf16<<<dim3(6, 64), blk, 0, stream>>>(
        hn, 768, tokin_wt, nullptr, nullptr, tt2, nullptr, nullptr, 0, 0, 1.f,
        hbuf, 768, 768);

    // ---- transformer blocks ----
    for (int i = 0; i < LLC; i++) {
        k_ln_mod<<<dim3(BN), blk, 0, stream>>>(
            hbuf, ln1_w + (size_t)i * 768, ln1_b + (size_t)i * 768,
            c1 + (size_t)i * 18432, hn);

        k_gemm_bf16<<<dim3(18, 64), blk, 0, stream>>>(
            hn, 768, qkv_wt + (size_t)i * 2304 * 768, qkv_b + (size_t)i * 2304,
            nullptr, nullptr, nullptr, nullptr, 0, 0, 1.f,
            big, 768, 2304);

        k_rope<<<dim3((BN * HHC * 32 + 255) / 256), blk, 0, stream>>>(big);
        k_attn_mfma<<<dim3(768), blk, 0, stream>>>(big);   // y -> q slot

        // h += RES_SCALE * (y@W + b) * g1
        k_gemm_bf16<<<dim3(6, 64), blk, 0, stream>>>(
            big, 2304, aproj_wt + (size_t)i * 768 * 768, aproj_b + (size_t)i * 768,
            nullptr, nullptr, hbuf, c1 + (size_t)i * 18432 + 1536, 2304, 0, RES_SCALE,
            hbuf, 768, 768);

        k_ln_mod<<<dim3(BN), blk, 0, stream>>>(
            hbuf, ln2_w + (size_t)i * 768, ln2_b + (size_t)i * 768,
            c2 + (size_t)i * 18432, hn);

        // m1 = gelu(hn @ w1 + b1)
        k_gemm_bf16<<<dim3(24, 64), blk, 0, stream>>>(
            hn, 768, mlp1_wt + (size_t)i * 3072 * 768, mlp_b1 + (size_t)i * 3072,
            nullptr, nullptr, nullptr, nullptr, 0, 1, 1.f,
            big, 768, 3072);

        // h += RES_SCALE * (m1 @ w2 + b2) * g2
        k_gemm_bf16<<<dim3(6, 64), blk, 0, stream>>>(
            big, 3072, mlp2_wt + (size_t)i * 768 * 3072, mlp_b2 + (size_t)i * 768,
            nullptr, nullptr, hbuf, c2 + (size_t)i * 18432 + 1536, 2304, 0, RES_SCALE,
            hbuf, 3072, 768);
    }

    // ---- epilogue ----
    k_gemm_bf16<<<dim3(2, 64), blk, 0, stream>>>(
        hbuf, 768, unemb_wt, unemb_b, nullptr, nullptr, nullptr, nullptr, 0, 0, 1.f,
        big, 768, 256);

    k_unpatch<<<dim3((BB * CC * 128 * 1024 + 255) / 256), blk, 0, stream>>>(
        x, big, out_gain, out);
}